// Round 13
// baseline (65.876 us; speedup 1.0000x reference)
//
#include <hip/hip_runtime.h>
#include <math.h>

// Problem geometry (fixed by reference)
#define BATCH   4096
#define NVARS   1024
#define ROWS_P0 8192
#define ROWS_S1 4096
#define ROWS_P2 8192
#define ROWS_S3 2048

#define LOG2E 1.4426950408889634f
#define LN2   0.6931471805599453f
#define NT    512      // threads per block; block owns 2 batch columns

typedef _Float16 h2 __attribute__((ext_vector_type(2)));
typedef float    f2 __attribute__((ext_vector_type(2)));

union H2U { h2 h; unsigned u; };

__device__ __forceinline__ float fexp2(float x) { return __builtin_amdgcn_exp2f(x); }
__device__ __forceinline__ float flog2(float x) { return __builtin_amdgcn_logf(x); }

// log2(1 - exp(x)) for x < 0, branchless, native-trans only (round-12 proven).
__device__ __forceinline__ float log1mexp_log2(float x) {
    float v = -x;
    float p = 1.0f + v * (-0.5f + v * (0.166666667f + v * (-0.0416666667f + v * 0.00833333333f)));
    float bs = v * p;                       // series value of 1-e^x  (|x| < ln2)
    float bd = 1.0f - fexp2(x * LOG2E);     // direct value of 1-e^x  (x <= -ln2, no cancellation)
    float arg = (x > -0.6931471805599453f) ? bs : bd;
    return flog2(arg);
}

// Pack two positive f32 (<=1.0) -> bf16x2 in one u32, round-half-up (round-6 proven).
__device__ __forceinline__ unsigned pk_bf16(float x, float y) {
    unsigned xb = __float_as_uint(x) + 0x8000u;
    unsigned yb = __float_as_uint(y) + 0x8000u;
    return (xb >> 16) | (yb & 0xFFFF0000u);
}
__device__ __forceinline__ float bf_lo(unsigned v) { return __uint_as_float(v << 16); }
__device__ __forceinline__ float bf_hi(unsigned v) { return __uint_as_float(v & 0xFFFF0000u); }
__device__ __forceinline__ f2 mk2(float a, float b) { f2 r; r.x = a; r.y = b; return r; }

// ---------------- single whole-circuit kernel: one block = 2 batch columns ----------------
// Round-13: halve the block (512 thr, 2 cols, 32 KiB LDS) -> 4 blocks/CU (32 waves/CU).
// Same per-chip LDS/VALU work (b32 gathers at 2 cols == b64 at 4 cols — issue-bound wash,
// rounds 6/7), but 4 independent phase-streams per CU, half-size barrier groups, finer
// scheduling tail -> targets the ~30% latency slack measured in round 12.
// Tables (u32/h2 views of one 32 KiB pool, overlaid phase by phase, full register holds):
//   enc : h2[2050]  log2-domain f16x2 (4B/row)   | p0/p2 : u32[8192] EXP2-domain bf16x2
//   s1  : h2[4096]  log2-domain f16x2            (one table live at a time)
// No max-subtraction: p0 in 2^[-80,0], realistic p2 >= 2^-110 > bf16 min-normal.
// fmax floors never trigger legitimately; they only stop pathological 0 -> -inf/NaN.
__global__ __launch_bounds__(NT, 8) void pipeline_kernel(const float* __restrict__ pos,   // [1024][4096]
                                                         const int4* __restrict__ idx0,   // [8192]
                                                         const int4* __restrict__ idx1,   // [4096][2]
                                                         const int4* __restrict__ idx2,   // [8192]
                                                         const int4* __restrict__ idx3,   // [2048][2]
                                                         float* __restrict__ out) {       // [2048][4096]
    __shared__ __align__(16) char pool[32768];
    unsigned* pu = reinterpret_cast<unsigned*>(pool);  // u32 view (p0/p2, raw stores)
    h2*       ph = reinterpret_cast<h2*>(pool);        // h2 view  (enc, s1 gathers)

    const int tid = threadIdx.x;
    // XCD-chunked bijective swizzle: 2048 blocks, 8 XCDs, 256 blocks/XCD chunk.
    const int bid = blockIdx.x;
    const int swz = ((bid & 7) << 8) | (bid >> 3);
    const int c0 = swz * 2;  // this block's two batch columns

    // ---- E: encode in-pipeline; thread tid handles vars tid and tid+512 ----
    {
        float2 A = *reinterpret_cast<const float2*>(pos + (size_t)tid * BATCH + c0);
        float2 B = *reinterpret_cast<const float2*>(pos + (size_t)(tid + NT) * BATCH + c0);
        H2U pA, nA, pB, nB;
        pA.h.x = (_Float16)(A.x * LOG2E);        pA.h.y = (_Float16)(A.y * LOG2E);
        nA.h.x = (_Float16)log1mexp_log2(A.x);   nA.h.y = (_Float16)log1mexp_log2(A.y);
        pB.h.x = (_Float16)(B.x * LOG2E);        pB.h.y = (_Float16)(B.y * LOG2E);
        nB.h.x = (_Float16)log1mexp_log2(B.x);   nB.h.y = (_Float16)log1mexp_log2(B.y);
        pu[2 + 2 * tid] = pA.u;
        pu[3 + 2 * tid] = nA.u;
        pu[2 + 2 * (tid + NT)] = pB.u;
        pu[3 + 2 * (tid + NT)] = nB.u;
        if (tid == 0) {
            pu[0] = 0xFC00FC00u;  // row 0: (-inf,-inf) f16 — never gathered (idx0 >= 1)
            pu[1] = 0u;           // row 1: (0,0) = log(1)
        }
    }
    __syncthreads();

    // ---- P0: gather-4 from enc (b32 h2), pk_f16 tree, 2^x, hold bf16x2 in regs ----
    unsigned hold0[16];
#pragma unroll
    for (int i = 0; i < ROWS_P0 / NT; ++i) {
        int r = tid + i * NT;
        int4 ix = idx0[r];
        h2 v0 = ph[ix.x], v1 = ph[ix.y], v2 = ph[ix.z], v3 = ph[ix.w];
        h2 s = (v0 + v1) + (v2 + v3);               // v_pk_add_f16 x3
        hold0[i] = pk_bf16(fexp2((float)s.x), fexp2((float)s.y));
    }
    __syncthreads();  // all P0 reads of enc done
#pragma unroll
    for (int i = 0; i < ROWS_P0 / NT; ++i) pu[tid + i * NT] = hold0[i];
    __syncthreads();

    // ---- S1: gather-8 from p0 (b32 bf16x2), pk_f32 tree, log2, hold f16x2 in regs ----
    unsigned hold1[8];
#pragma unroll
    for (int i = 0; i < ROWS_S1 / NT; ++i) {
        int r = tid + i * NT;
        int4 a = idx1[2 * r], b = idx1[2 * r + 1];
        unsigned u0 = pu[a.x], u1 = pu[a.y], u2 = pu[a.z], u3 = pu[a.w];
        unsigned u4 = pu[b.x], u5 = pu[b.y], u6 = pu[b.z], u7 = pu[b.w];
        f2 ab = ((mk2(bf_lo(u0), bf_hi(u0)) + mk2(bf_lo(u1), bf_hi(u1))) +
                 (mk2(bf_lo(u2), bf_hi(u2)) + mk2(bf_lo(u3), bf_hi(u3)))) +
                ((mk2(bf_lo(u4), bf_hi(u4)) + mk2(bf_lo(u5), bf_hi(u5))) +
                 (mk2(bf_lo(u6), bf_hi(u6)) + mk2(bf_lo(u7), bf_hi(u7))));
        ab = __builtin_elementwise_max(ab, mk2(1e-37f, 1e-37f));
        H2U o;
        o.h.x = (_Float16)flog2(ab.x);
        o.h.y = (_Float16)flog2(ab.y);
        hold1[i] = o.u;
    }
    __syncthreads();  // all S1 reads of p0 done
#pragma unroll
    for (int i = 0; i < ROWS_S1 / NT; ++i) pu[tid + i * NT] = hold1[i];
    __syncthreads();

    // ---- P2: gather-4 from s1 (b32 h2), pk_f16 tree, 2^x, hold bf16x2 in regs ----
    unsigned hold2[16];
#pragma unroll
    for (int i = 0; i < ROWS_P2 / NT; ++i) {
        int r = tid + i * NT;
        int4 ix = idx2[r];
        h2 v0 = ph[ix.x], v1 = ph[ix.y], v2 = ph[ix.z], v3 = ph[ix.w];
        h2 s = (v0 + v1) + (v2 + v3);               // v_pk_add_f16 x3
        hold2[i] = pk_bf16(fexp2((float)s.x), fexp2((float)s.y));
    }
    __syncthreads();  // all P2 reads of s1 done
#pragma unroll
    for (int i = 0; i < ROWS_P2 / NT; ++i) pu[tid + i * NT] = hold2[i];
    __syncthreads();

    // ---- S3: gather-8 from p2 (b32 bf16x2), pk_f32 tree, log2 -> ln, float2 out ----
#pragma unroll
    for (int i = 0; i < ROWS_S3 / NT; ++i) {
        int r = tid + i * NT;
        int4 a = idx3[2 * r], b = idx3[2 * r + 1];
        unsigned u0 = pu[a.x], u1 = pu[a.y], u2 = pu[a.z], u3 = pu[a.w];
        unsigned u4 = pu[b.x], u5 = pu[b.y], u6 = pu[b.z], u7 = pu[b.w];
        f2 ab = ((mk2(bf_lo(u0), bf_hi(u0)) + mk2(bf_lo(u1), bf_hi(u1))) +
                 (mk2(bf_lo(u2), bf_hi(u2)) + mk2(bf_lo(u3), bf_hi(u3)))) +
                ((mk2(bf_lo(u4), bf_hi(u4)) + mk2(bf_lo(u5), bf_hi(u5))) +
                 (mk2(bf_lo(u6), bf_hi(u6)) + mk2(bf_lo(u7), bf_hi(u7))));
        ab = __builtin_elementwise_max(ab, mk2(1e-37f, 1e-37f));
        float2 o;
        o.x = flog2(ab.x) * LN2;
        o.y = flog2(ab.y) * LN2;
        // direct transposed store: 8B per lane; line-sharing blocks co-reside per XCD
        *reinterpret_cast<float2*>(out + (size_t)r * BATCH + c0) = o;
    }
}

extern "C" void kernel_launch(void* const* d_in, const int* in_sizes, int n_in,
                              void* d_out, int out_size, void* d_ws, size_t ws_size,
                              hipStream_t stream) {
    const float* pos  = (const float*)d_in[0];
    const int4*  idx0 = (const int4*)d_in[1];
    const int4*  idx1 = (const int4*)d_in[2];
    const int4*  idx2 = (const int4*)d_in[3];
    const int4*  idx3 = (const int4*)d_in[4];
    float*       out  = (float*)d_out;
    (void)d_ws; (void)ws_size;

    // single kernel: whole circuit in LDS, one block per 2 columns (4 blocks/CU)
    pipeline_kernel<<<dim3(BATCH / 2), dim3(NT), 0, stream>>>(pos, idx0, idx1, idx2, idx3, out);
}

// Round 14
// 47.453 us; speedup vs baseline: 1.3882x; 1.3882x over previous
//
#include <hip/hip_runtime.h>
#include <math.h>

// Problem geometry (fixed by reference)
#define BATCH   4096
#define NVARS   1024
#define ROWS_P0 8192
#define ROWS_S1 4096
#define ROWS_P2 8192
#define ROWS_S3 2048

#define LOG2E 1.4426950408889634f
#define LN2   0.6931471805599453f
#define NT    1024

typedef _Float16 h4 __attribute__((ext_vector_type(4)));
typedef float    f2 __attribute__((ext_vector_type(2)));

union HU { h4 h; uint2 u; };

__device__ __forceinline__ float fexp2(float x) { return __builtin_amdgcn_exp2f(x); }
__device__ __forceinline__ float flog2(float x) { return __builtin_amdgcn_logf(x); }

// log2(1 - exp(x)) for x < 0, branchless, native-trans only (round-12 proven).
__device__ __forceinline__ float log1mexp_log2(float x) {
    float v = -x;
    float p = 1.0f + v * (-0.5f + v * (0.166666667f + v * (-0.0416666667f + v * 0.00833333333f)));
    float bs = v * p;                       // series value of 1-e^x  (|x| < ln2)
    float bd = 1.0f - fexp2(x * LOG2E);     // direct value of 1-e^x  (x <= -ln2, no cancellation)
    float arg = (x > -0.6931471805599453f) ? bs : bd;
    return flog2(arg);
}

// Pack two positive f32 (<=1.0) -> bf16x2 in one u32, round-half-up (round-6 proven).
__device__ __forceinline__ unsigned pk_bf16(float x, float y) {
    unsigned xb = __float_as_uint(x) + 0x8000u;
    unsigned yb = __float_as_uint(y) + 0x8000u;
    return (xb >> 16) | (yb & 0xFFFF0000u);
}
__device__ __forceinline__ float bf_lo(unsigned v) { return __uint_as_float(v << 16); }
__device__ __forceinline__ float bf_hi(unsigned v) { return __uint_as_float(v & 0xFFFF0000u); }
__device__ __forceinline__ f2 mk2(float a, float b) { f2 r; r.x = a; r.y = b; return r; }

// ---------------- single whole-circuit kernel: one block = 4 batch columns ----------------
// Round-14 = round-12 base (proven 46.0us) + contiguous ds_write_b128 table stores.
// Thread t owns ADJACENT row pairs (2(t+1024i), 2(t+1024i)+1): the pair packs into one
// uint4 -> one b128 store at 16B/lane contiguous stride (bank-optimal, 85B/cyc vs 64),
// halving LDS write instructions (22 -> 11/thread). Gathers/overlays/holds unchanged.
// Round-13 lessons honored: b64 gathers at 4 cols (b32 doubles conflict cycles), 16B
// output stores (8B stores write-amplify), XCD-chunked swizzle for write-combining.
//   enc : h4[2050]    log2-domain f16x4   | p0/p2 : uint2[8192] EXP2-domain bf16x4
//   s1  : h4[4096]    log2-domain f16x4   (tables overlay one another phase by phase)
// No max-subtraction: p0 in 2^[-80,0], realistic p2 >= 2^-110 > bf16 min-normal.
// fmax floors never trigger legitimately; they only stop pathological 0 -> -inf/NaN.
__global__ __launch_bounds__(NT, 8) void pipeline_kernel(const float* __restrict__ pos,   // [1024][4096]
                                                         const int4* __restrict__ idx0,   // [8192]
                                                         const int4* __restrict__ idx1,   // [4096][2]
                                                         const int4* __restrict__ idx2,   // [8192]
                                                         const int4* __restrict__ idx3,   // [2048][2]
                                                         float* __restrict__ out) {       // [2048][4096]
    __shared__ __align__(16) char pool[65536];
    h4*    ph = reinterpret_cast<h4*>(pool);       // h4 row view   (enc, s1 gathers)
    uint2* pu = reinterpret_cast<uint2*>(pool);    // uint2 row view (p0/p2 gathers)
    uint4* p4 = reinterpret_cast<uint4*>(pool);    // uint4 pair view (wide stores)

    const int tid = threadIdx.x;
    // XCD-chunked bijective swizzle: 1024 blocks, 8 XCDs, 128 blocks/XCD chunk.
    const int bid = blockIdx.x;
    const int swz = ((bid & 7) << 7) | (bid >> 3);
    const int c0 = swz * 4;  // this block's four batch columns

    // ---- E: encode in-pipeline; one b128 store (rows 2+2t, 3+2t = uint4 slot t+1) ----
    {
        const float4 a = *reinterpret_cast<const float4*>(pos + (size_t)tid * BATCH + c0);
        HU ep, en;
        ep.h.x = (_Float16)(a.x * LOG2E); ep.h.y = (_Float16)(a.y * LOG2E);
        ep.h.z = (_Float16)(a.z * LOG2E); ep.h.w = (_Float16)(a.w * LOG2E);
        en.h.x = (_Float16)log1mexp_log2(a.x); en.h.y = (_Float16)log1mexp_log2(a.y);
        en.h.z = (_Float16)log1mexp_log2(a.z); en.h.w = (_Float16)log1mexp_log2(a.w);
        uint4 e4;
        e4.x = ep.u.x; e4.y = ep.u.y; e4.z = en.u.x; e4.w = en.u.y;
        p4[tid + 1] = e4;
        if (tid == 0) {
            uint4 hdr;
            hdr.x = 0xFC00FC00u; hdr.y = 0xFC00FC00u;  // row 0: -inf x4 (never gathered, idx0>=1)
            hdr.z = 0u;          hdr.w = 0u;           // row 1: 0 x4 = log(1)
            p4[0] = hdr;
        }
    }
    __syncthreads();

    // ---- P0: gather-4 from enc (b64), pk_f16 tree, 2^x; rows 2(t+1024i)+j ----
    uint2 hold0[8];
#pragma unroll
    for (int i = 0; i < 4; ++i) {
#pragma unroll
        for (int j = 0; j < 2; ++j) {
            int r = 2 * (tid + 1024 * i) + j;
            int4 ix = idx0[r];
            h4 v0 = ph[ix.x], v1 = ph[ix.y], v2 = ph[ix.z], v3 = ph[ix.w];
            h4 s = (v0 + v1) + (v2 + v3);             // v_pk_add_f16 x6
            hold0[2 * i + j] = make_uint2(pk_bf16(fexp2((float)s.x), fexp2((float)s.y)),
                                          pk_bf16(fexp2((float)s.z), fexp2((float)s.w)));
        }
    }
    __syncthreads();  // all P0 reads of enc done
#pragma unroll
    for (int i = 0; i < 4; ++i) {
        uint4 w;
        w.x = hold0[2 * i].x;     w.y = hold0[2 * i].y;
        w.z = hold0[2 * i + 1].x; w.w = hold0[2 * i + 1].y;
        p4[tid + 1024 * i] = w;   // rows 2(t+1024i), +1 — contiguous b128
    }
    __syncthreads();

    // ---- S1: gather-8 from p0 (b64 bf16x4), pk_f32 trees, log2; rows 2(t+1024i)+j ----
    uint2 hold1[4];
#pragma unroll
    for (int i = 0; i < 2; ++i) {
#pragma unroll
        for (int j = 0; j < 2; ++j) {
            int r = 2 * (tid + 1024 * i) + j;
            int4 a = idx1[2 * r], b = idx1[2 * r + 1];
            uint2 u0 = pu[a.x], u1 = pu[a.y], u2 = pu[a.z], u3 = pu[a.w];
            uint2 u4 = pu[b.x], u5 = pu[b.y], u6 = pu[b.z], u7 = pu[b.w];
            f2 ab = ((mk2(bf_lo(u0.x), bf_hi(u0.x)) + mk2(bf_lo(u1.x), bf_hi(u1.x))) +
                     (mk2(bf_lo(u2.x), bf_hi(u2.x)) + mk2(bf_lo(u3.x), bf_hi(u3.x)))) +
                    ((mk2(bf_lo(u4.x), bf_hi(u4.x)) + mk2(bf_lo(u5.x), bf_hi(u5.x))) +
                     (mk2(bf_lo(u6.x), bf_hi(u6.x)) + mk2(bf_lo(u7.x), bf_hi(u7.x))));
            f2 cd = ((mk2(bf_lo(u0.y), bf_hi(u0.y)) + mk2(bf_lo(u1.y), bf_hi(u1.y))) +
                     (mk2(bf_lo(u2.y), bf_hi(u2.y)) + mk2(bf_lo(u3.y), bf_hi(u3.y)))) +
                    ((mk2(bf_lo(u4.y), bf_hi(u4.y)) + mk2(bf_lo(u5.y), bf_hi(u5.y))) +
                     (mk2(bf_lo(u6.y), bf_hi(u6.y)) + mk2(bf_lo(u7.y), bf_hi(u7.y))));
            ab = __builtin_elementwise_max(ab, mk2(1e-37f, 1e-37f));
            cd = __builtin_elementwise_max(cd, mk2(1e-37f, 1e-37f));
            HU o;
            o.h.x = (_Float16)flog2(ab.x);
            o.h.y = (_Float16)flog2(ab.y);
            o.h.z = (_Float16)flog2(cd.x);
            o.h.w = (_Float16)flog2(cd.y);
            hold1[2 * i + j] = o.u;
        }
    }
    __syncthreads();  // all S1 reads of p0 done
#pragma unroll
    for (int i = 0; i < 2; ++i) {
        uint4 w;
        w.x = hold1[2 * i].x;     w.y = hold1[2 * i].y;
        w.z = hold1[2 * i + 1].x; w.w = hold1[2 * i + 1].y;
        p4[tid + 1024 * i] = w;   // s1 rows 2(t+1024i), +1 — contiguous b128
    }
    __syncthreads();

    // ---- P2: gather-4 from s1 (b64), pk_f16 tree, 2^x; rows 2(t+1024i)+j ----
    uint2 hold2[8];
#pragma unroll
    for (int i = 0; i < 4; ++i) {
#pragma unroll
        for (int j = 0; j < 2; ++j) {
            int r = 2 * (tid + 1024 * i) + j;
            int4 ix = idx2[r];
            h4 v0 = ph[ix.x], v1 = ph[ix.y], v2 = ph[ix.z], v3 = ph[ix.w];
            h4 s = (v0 + v1) + (v2 + v3);             // v_pk_add_f16 x6
            hold2[2 * i + j] = make_uint2(pk_bf16(fexp2((float)s.x), fexp2((float)s.y)),
                                          pk_bf16(fexp2((float)s.z), fexp2((float)s.w)));
        }
    }
    __syncthreads();  // all P2 reads of s1 done
#pragma unroll
    for (int i = 0; i < 4; ++i) {
        uint4 w;
        w.x = hold2[2 * i].x;     w.y = hold2[2 * i].y;
        w.z = hold2[2 * i + 1].x; w.w = hold2[2 * i + 1].y;
        p4[tid + 1024 * i] = w;   // p2 rows 2(t+1024i), +1 — contiguous b128
    }
    __syncthreads();

    // ---- S3: gather-8 from p2 (b64), pk_f32 trees, log2 -> ln, float4 out; rows 2t,2t+1 ----
#pragma unroll
    for (int j = 0; j < 2; ++j) {
        int r = 2 * tid + j;
        int4 a = idx3[2 * r], b = idx3[2 * r + 1];
        uint2 u0 = pu[a.x], u1 = pu[a.y], u2 = pu[a.z], u3 = pu[a.w];
        uint2 u4 = pu[b.x], u5 = pu[b.y], u6 = pu[b.z], u7 = pu[b.w];
        f2 ab = ((mk2(bf_lo(u0.x), bf_hi(u0.x)) + mk2(bf_lo(u1.x), bf_hi(u1.x))) +
                 (mk2(bf_lo(u2.x), bf_hi(u2.x)) + mk2(bf_lo(u3.x), bf_hi(u3.x)))) +
                ((mk2(bf_lo(u4.x), bf_hi(u4.x)) + mk2(bf_lo(u5.x), bf_hi(u5.x))) +
                 (mk2(bf_lo(u6.x), bf_hi(u6.x)) + mk2(bf_lo(u7.x), bf_hi(u7.x))));
        f2 cd = ((mk2(bf_lo(u0.y), bf_hi(u0.y)) + mk2(bf_lo(u1.y), bf_hi(u1.y))) +
                 (mk2(bf_lo(u2.y), bf_hi(u2.y)) + mk2(bf_lo(u3.y), bf_hi(u3.y)))) +
                ((mk2(bf_lo(u4.y), bf_hi(u4.y)) + mk2(bf_lo(u5.y), bf_hi(u5.y))) +
                 (mk2(bf_lo(u6.y), bf_hi(u6.y)) + mk2(bf_lo(u7.y), bf_hi(u7.y))));
        ab = __builtin_elementwise_max(ab, mk2(1e-37f, 1e-37f));
        cd = __builtin_elementwise_max(cd, mk2(1e-37f, 1e-37f));
        float4 o4;
        o4.x = flog2(ab.x) * LN2;
        o4.y = flog2(ab.y) * LN2;
        o4.z = flog2(cd.x) * LN2;
        o4.w = flog2(cd.y) * LN2;
        // direct transposed store: 16B per lane; line-sharing blocks co-reside per XCD
        reinterpret_cast<float4*>(out)[(size_t)r * (BATCH / 4) + swz] = o4;
    }
}

extern "C" void kernel_launch(void* const* d_in, const int* in_sizes, int n_in,
                              void* d_out, int out_size, void* d_ws, size_t ws_size,
                              hipStream_t stream) {
    const float* pos  = (const float*)d_in[0];
    const int4*  idx0 = (const int4*)d_in[1];
    const int4*  idx1 = (const int4*)d_in[2];
    const int4*  idx2 = (const int4*)d_in[3];
    const int4*  idx3 = (const int4*)d_in[4];
    float*       out  = (float*)d_out;
    (void)d_ws; (void)ws_size;

    // single kernel: whole circuit in LDS, one block per 4 columns (2 blocks/CU)
    pipeline_kernel<<<dim3(BATCH / 4), dim3(NT), 0, stream>>>(pos, idx0, idx1, idx2, idx3, out);
}

// Round 15
// 46.181 us; speedup vs baseline: 1.4265x; 1.0276x over previous
//
#include <hip/hip_runtime.h>
#include <math.h>

// Problem geometry (fixed by reference)
#define BATCH   4096
#define NVARS   1024
#define ROWS_P0 8192
#define ROWS_S1 4096
#define ROWS_P2 8192
#define ROWS_S3 2048
#define ENCROWS 2050

#define LOG2E 1.4426950408889634f
#define LN2   0.6931471805599453f

typedef _Float16 h4 __attribute__((ext_vector_type(4)));
typedef float    f2 __attribute__((ext_vector_type(2)));

union HU { h4 h; uint2 u; };

__device__ __forceinline__ float fexp2(float x) { return __builtin_amdgcn_exp2f(x); }
__device__ __forceinline__ float flog2(float x) { return __builtin_amdgcn_logf(x); }

// log2(1 - exp(x)) for x < 0, branchless, native-trans only (~12 VALU).
// x <= -ln2 : 1 - 2^(x*log2e) has no cancellation -> direct.
// x >  -ln2 : 1 - e^-v = v*(1 - v/2 + v^2/6 - v^3/24 + v^4/120), v = -x in (0, ln2);
//             truncation <= 2.2e-4 relative -> ~3e-4 log2 abs, under the f16-storage
//             quantization this feeds (and way under the 0.063 output threshold).
__device__ __forceinline__ float log1mexp_log2(float x) {
    float v = -x;
    float p = 1.0f + v * (-0.5f + v * (0.166666667f + v * (-0.0416666667f + v * 0.00833333333f)));
    float bs = v * p;                       // series value of 1-e^x
    float bd = 1.0f - fexp2(x * LOG2E);     // direct value of 1-e^x
    float arg = (x > -0.6931471805599453f) ? bs : bd;
    return flog2(arg);
}

// Pack two positive f32 (<=1.0) -> bf16x2 in one u32, round-half-up (5 VALU ops).
__device__ __forceinline__ unsigned pk_bf16(float x, float y) {
    unsigned xb = __float_as_uint(x) + 0x8000u;
    unsigned yb = __float_as_uint(y) + 0x8000u;
    return (xb >> 16) | (yb & 0xFFFF0000u);
}
__device__ __forceinline__ float bf_lo(unsigned v) { return __uint_as_float(v << 16); }
__device__ __forceinline__ float bf_hi(unsigned v) { return __uint_as_float(v & 0xFFFF0000u); }
__device__ __forceinline__ f2 mk2(float a, float b) { f2 r; r.x = a; r.y = b; return r; }

// ---------------- single whole-circuit kernel: one block = 4 batch columns ----------------
// FINAL (= round-12, best measured 46.0us): encode fused with native-trans log1mexp,
// pos read directly as one float4/thread (lines shared by 8 swz-adjacent blocks ->
// same-XCD L2). Packed math, register-deferred tables (one live at a time, 64 KiB LDS
// -> 2 blocks/CU), all-b64 LDS gathers serving 4 columns, bijective XCD-chunked swizzle
// for output write-combining.
// Probed and rejected: 512-thr blocks (b32 gathers double conflict cycles, 8B stores
// write-amplify — r13), b128 paired table writes (neutral, writes off critical path —
// r14), separate encode kernel (launch+round-trip costs more than it saves — r11).
//   enc : h4[2050]    log2-domain f16x4   | p0/p2 : uint2[8192] EXP2-domain bf16x4
//   s1  : h4[4096]    log2-domain f16x4   (tables overlay one another phase by phase)
// No max-subtraction: p0 in 2^[-80,0], realistic p2 >= 2^-110 > bf16 min-normal.
// fmax floors never trigger legitimately; they only stop pathological 0 -> -inf/NaN.
__global__ __launch_bounds__(1024, 8) void pipeline_kernel(const float* __restrict__ pos,   // [1024][4096]
                                                           const int4* __restrict__ idx0,   // [8192]
                                                           const int4* __restrict__ idx1,   // [4096][2]
                                                           const int4* __restrict__ idx2,   // [8192]
                                                           const int4* __restrict__ idx3,   // [2048][2]
                                                           float* __restrict__ out) {       // [2048][4096]
    __shared__ __align__(16) char pool[65536];
    h4*    enc = reinterpret_cast<h4*>(pool);      // [2050]  (16400 B)
    uint2* p0  = reinterpret_cast<uint2*>(pool);   // [8192]  (65536 B)
    h4*    s1  = reinterpret_cast<h4*>(pool);      // [4096]  (32768 B)
    uint2* p2  = reinterpret_cast<uint2*>(pool);   // [8192]  (65536 B)

    const int tid = threadIdx.x;
    // XCD-chunked bijective swizzle: 1024 blocks, 8 XCDs, 128 blocks/XCD chunk.
    const int bid = blockIdx.x;
    const int swz = ((bid & 7) << 7) | (bid >> 3);
    const int c0 = swz * 4;  // this block's four batch columns

    // ---- E: encode in-pipeline (fast log1mexp), thread tid handles var tid ----
    {
        const float4 a = *reinterpret_cast<const float4*>(pos + (size_t)tid * BATCH + c0);
        HU ep, en;
        ep.h.x = (_Float16)(a.x * LOG2E); ep.h.y = (_Float16)(a.y * LOG2E);
        ep.h.z = (_Float16)(a.z * LOG2E); ep.h.w = (_Float16)(a.w * LOG2E);
        en.h.x = (_Float16)log1mexp_log2(a.x); en.h.y = (_Float16)log1mexp_log2(a.y);
        en.h.z = (_Float16)log1mexp_log2(a.z); en.h.w = (_Float16)log1mexp_log2(a.w);
        uint2* encu = reinterpret_cast<uint2*>(pool);
        encu[2 + 2 * tid] = ep.u;
        encu[3 + 2 * tid] = en.u;
        if (tid == 0) {
            HU ni, z;
            ni.h.x = ni.h.y = ni.h.z = ni.h.w = (_Float16)(-INFINITY);  // row 0: never gathered (idx0>=1)
            z.h.x = z.h.y = z.h.z = z.h.w = (_Float16)0.f;              // row 1: log(1)
            encu[0] = ni.u;
            encu[1] = z.u;
        }
    }
    __syncthreads();

    // ---- P0: gather-4 from enc (b64), packed-f16 sum tree, 2^x, hold bf16x4 in regs ----
    uint2 hold0[8];
#pragma unroll
    for (int i = 0; i < ROWS_P0 / 1024; ++i) {
        int r = tid + i * 1024;
        int4 ix = idx0[r];
        h4 v0 = enc[ix.x], v1 = enc[ix.y], v2 = enc[ix.z], v3 = enc[ix.w];
        h4 s = (v0 + v1) + (v2 + v3);                 // v_pk_add_f16 x6
        hold0[i] = make_uint2(pk_bf16(fexp2((float)s.x), fexp2((float)s.y)),
                              pk_bf16(fexp2((float)s.z), fexp2((float)s.w)));
    }
    __syncthreads();  // all P0 reads of enc done
#pragma unroll
    for (int i = 0; i < ROWS_P0 / 1024; ++i) p0[tid + i * 1024] = hold0[i];
    __syncthreads();

    // ---- S1: gather-8 from p0 (b64, exp2-domain), packed-f32 sum trees, log2, hold f16x4 ----
    h4 hold1[4];
#pragma unroll
    for (int i = 0; i < ROWS_S1 / 1024; ++i) {
        int r = tid + i * 1024;
        int4 a = idx1[2 * r], b = idx1[2 * r + 1];
        uint2 u0 = p0[a.x], u1 = p0[a.y], u2 = p0[a.z], u3 = p0[a.w];
        uint2 u4 = p0[b.x], u5 = p0[b.y], u6 = p0[b.z], u7 = p0[b.w];
        f2 ab = (mk2(bf_lo(u0.x), bf_hi(u0.x)) + mk2(bf_lo(u1.x), bf_hi(u1.x))) +
                (mk2(bf_lo(u2.x), bf_hi(u2.x)) + mk2(bf_lo(u3.x), bf_hi(u3.x)));
        ab = ab + ((mk2(bf_lo(u4.x), bf_hi(u4.x)) + mk2(bf_lo(u5.x), bf_hi(u5.x))) +
                   (mk2(bf_lo(u6.x), bf_hi(u6.x)) + mk2(bf_lo(u7.x), bf_hi(u7.x))));
        f2 cd = (mk2(bf_lo(u0.y), bf_hi(u0.y)) + mk2(bf_lo(u1.y), bf_hi(u1.y))) +
                (mk2(bf_lo(u2.y), bf_hi(u2.y)) + mk2(bf_lo(u3.y), bf_hi(u3.y)));
        cd = cd + ((mk2(bf_lo(u4.y), bf_hi(u4.y)) + mk2(bf_lo(u5.y), bf_hi(u5.y))) +
                   (mk2(bf_lo(u6.y), bf_hi(u6.y)) + mk2(bf_lo(u7.y), bf_hi(u7.y))));
        ab = __builtin_elementwise_max(ab, mk2(1e-37f, 1e-37f));
        cd = __builtin_elementwise_max(cd, mk2(1e-37f, 1e-37f));
        h4 o;
        o.x = (_Float16)flog2(ab.x);
        o.y = (_Float16)flog2(ab.y);
        o.z = (_Float16)flog2(cd.x);
        o.w = (_Float16)flog2(cd.y);
        hold1[i] = o;
    }
    __syncthreads();  // all S1 reads of p0 done
#pragma unroll
    for (int i = 0; i < ROWS_S1 / 1024; ++i) s1[tid + i * 1024] = hold1[i];
    __syncthreads();

    // ---- P2: gather-4 from s1 (b64), packed-f16 sum tree, 2^x, hold bf16x4 in regs ----
    uint2 hold2[8];
#pragma unroll
    for (int i = 0; i < ROWS_P2 / 1024; ++i) {
        int r = tid + i * 1024;
        int4 ix = idx2[r];
        h4 v0 = s1[ix.x], v1 = s1[ix.y], v2 = s1[ix.z], v3 = s1[ix.w];
        h4 s = (v0 + v1) + (v2 + v3);                 // v_pk_add_f16 x6
        hold2[i] = make_uint2(pk_bf16(fexp2((float)s.x), fexp2((float)s.y)),
                              pk_bf16(fexp2((float)s.z), fexp2((float)s.w)));
    }
    __syncthreads();  // all P2 reads of s1 done
#pragma unroll
    for (int i = 0; i < ROWS_P2 / 1024; ++i) p2[tid + i * 1024] = hold2[i];
    __syncthreads();

    // ---- S3: gather-8 from p2 (b64), packed-f32 trees, log2 -> ln, direct float4 out ----
#pragma unroll
    for (int i = 0; i < ROWS_S3 / 1024; ++i) {
        int r = tid + i * 1024;
        int4 a = idx3[2 * r], b = idx3[2 * r + 1];
        uint2 u0 = p2[a.x], u1 = p2[a.y], u2 = p2[a.z], u3 = p2[a.w];
        uint2 u4 = p2[b.x], u5 = p2[b.y], u6 = p2[b.z], u7 = p2[b.w];
        f2 ab = (mk2(bf_lo(u0.x), bf_hi(u0.x)) + mk2(bf_lo(u1.x), bf_hi(u1.x))) +
                (mk2(bf_lo(u2.x), bf_hi(u2.x)) + mk2(bf_lo(u3.x), bf_hi(u3.x)));
        ab = ab + ((mk2(bf_lo(u4.x), bf_hi(u4.x)) + mk2(bf_lo(u5.x), bf_hi(u5.x))) +
                   (mk2(bf_lo(u6.x), bf_hi(u6.x)) + mk2(bf_lo(u7.x), bf_hi(u7.x))));
        f2 cd = (mk2(bf_lo(u0.y), bf_hi(u0.y)) + mk2(bf_lo(u1.y), bf_hi(u1.y))) +
                (mk2(bf_lo(u2.y), bf_hi(u2.y)) + mk2(bf_lo(u3.y), bf_hi(u3.y)));
        cd = cd + ((mk2(bf_lo(u4.y), bf_hi(u4.y)) + mk2(bf_lo(u5.y), bf_hi(u5.y))) +
                   (mk2(bf_lo(u6.y), bf_hi(u6.y)) + mk2(bf_lo(u7.y), bf_hi(u7.y))));
        ab = __builtin_elementwise_max(ab, mk2(1e-37f, 1e-37f));
        cd = __builtin_elementwise_max(cd, mk2(1e-37f, 1e-37f));
        float4 o4;
        o4.x = flog2(ab.x) * LN2;
        o4.y = flog2(ab.y) * LN2;
        o4.z = flog2(cd.x) * LN2;
        o4.w = flog2(cd.y) * LN2;
        // direct transposed store: 16B per lane; line-sharing blocks co-reside per XCD
        reinterpret_cast<float4*>(out)[(size_t)r * (BATCH / 4) + swz] = o4;
    }
}

extern "C" void kernel_launch(void* const* d_in, const int* in_sizes, int n_in,
                              void* d_out, int out_size, void* d_ws, size_t ws_size,
                              hipStream_t stream) {
    const float* pos  = (const float*)d_in[0];
    const int4*  idx0 = (const int4*)d_in[1];
    const int4*  idx1 = (const int4*)d_in[2];
    const int4*  idx2 = (const int4*)d_in[3];
    const int4*  idx3 = (const int4*)d_in[4];
    float*       out  = (float*)d_out;
    (void)d_ws; (void)ws_size;

    // single kernel: whole circuit in LDS, one block per 4 columns (2 blocks/CU)
    pipeline_kernel<<<dim3(BATCH / 4), dim3(1024), 0, stream>>>(pos, idx0, idx1, idx2, idx3, out);
}